// Round 13
// baseline (402.415 us; speedup 1.0000x reference)
//
#include <hip/hip_runtime.h>
#include <cstdint>
#include <cstddef>

// Problem constants
#define B_  2
#define T_  1024
#define DM  1024
#define H_  16
#define DK_ 64
#define TOPK 128

typedef unsigned short ushort_t;
typedef __attribute__((ext_vector_type(8))) short short8;
typedef __attribute__((ext_vector_type(8))) unsigned short u16x8;
typedef __attribute__((ext_vector_type(4))) float f32x4;

// monotone map bf16 bits -> u16 (bigger key == bigger float)
__device__ __forceinline__ unsigned fkey16(unsigned b) {
  return (b & 0x8000u) ? (0xffffu & ~b) : (b | 0x8000u);
}

// round-to-nearest-even float -> bf16
__device__ __forceinline__ ushort_t f2bf(float f) {
  unsigned u = __float_as_uint(f);
  return (ushort_t)((u + 0x7fffu + ((u >> 16) & 1u)) >> 16);
}
__device__ __forceinline__ float bf2f(ushort_t u) {
  return __uint_as_float((unsigned)u << 16);
}

// async global->LDS 16B copy (linear LDS dest; global src may be swizzled)
__device__ __forceinline__ void gload_lds16(const ushort_t* g, ushort_t* l) {
  __builtin_amdgcn_global_load_lds(
      (const __attribute__((address_space(1))) unsigned int*)(const void*)g,
      (__attribute__((address_space(3))) unsigned int*)(void*)l, 16, 0, 0);
}

// ---------- fused bf16 casts: x + 5 weights in one launch --------------------
__global__ __launch_bounds__(256) void cast6_kernel(
    const float* __restrict__ x, const float* __restrict__ wq,
    const float* __restrict__ wk, const float* __restrict__ wre,
    const float* __restrict__ wim, const float* __restrict__ wv,
    ushort_t* __restrict__ xb, ushort_t* __restrict__ w5b) {
  int z = blockIdx.y;
  const float* src; ushort_t* dst; int n4;
  switch (z) {
    case 0: src = x;   dst = xb;                 n4 = 524288; break;
    case 1: src = wq;  dst = w5b;                n4 = 262144; break;
    case 2: src = wk;  dst = w5b + 1048576;      n4 = 262144; break;
    case 3: src = wre; dst = w5b + 2097152;      n4 = 262144; break;
    case 4: src = wim; dst = w5b + 3145728;      n4 = 262144; break;
    default: src = wv; dst = w5b + 4194304;      n4 = 262144; break;
  }
  int i = blockIdx.x * 256 + threadIdx.x;
  if (i < n4) {
    float4 v = ((const float4*)src)[i];
    ushort4 o;
    o.x = f2bf(v.x); o.y = f2bf(v.y); o.z = f2bf(v.z); o.w = f2bf(v.w);
    ((ushort4*)dst)[i] = o;
  }
}

__global__ __launch_bounds__(256) void cast_bf16_kernel(
    const float* __restrict__ in, ushort_t* __restrict__ out, int n4) {
  int i = blockIdx.x * 256 + threadIdx.x;
  if (i < n4) {
    float4 v = ((const float4*)in)[i];
    ushort4 o;
    o.x = f2bf(v.x); o.y = f2bf(v.y); o.z = f2bf(v.z); o.w = f2bf(v.w);
    ((ushort4*)out)[i] = o;
  }
}

// ---------------------------------------------------------------------------
// bf16 MFMA NT GEMM core: 128x128 tile, BK=64, 4 waves (2x2), fp32 acc.
// ---------------------------------------------------------------------------
template<int KDIM>
__device__ __forceinline__ void gemm_core(
    const ushort_t* __restrict__ Ab, const ushort_t* __restrict__ Bb,
    ushort_t* ldsA, ushort_t* ldsB, int tid, f32x4 acc[4][4]) {
  const int lane = tid & 63, wid = tid >> 6;
  const int wr = (wid >> 1) * 64, wc = (wid & 1) * 64;
  const int l15 = lane & 15, l4 = lane >> 4;
  for (int k0 = 0; k0 < KDIM; k0 += 64) {
    #pragma unroll
    for (int i = 0; i < 4; ++i) {
      int cid = tid + 256 * i;          // 1024 chunks of 16B per tile
      int row = cid >> 3, slot = cid & 7;
      int gc = slot ^ (row & 7);        // pre-swizzled global chunk
      gload_lds16(&Ab[(size_t)row * KDIM + k0 + gc * 8], &ldsA[cid * 8]);
      gload_lds16(&Bb[(size_t)row * KDIM + k0 + gc * 8], &ldsB[cid * 8]);
    }
    __syncthreads();
    #pragma unroll
    for (int ks = 0; ks < 2; ++ks) {
      short8 af[4], bfr[4];
      #pragma unroll
      for (int m = 0; m < 4; ++m) {
        int r = wr + m * 16 + l15;
        int c = ks * 4 + l4;
        af[m] = *(const short8*)&ldsA[r * 64 + (c ^ (r & 7)) * 8];
      }
      #pragma unroll
      for (int n = 0; n < 4; ++n) {
        int r = wc + n * 16 + l15;
        int c = ks * 4 + l4;
        bfr[n] = *(const short8*)&ldsB[r * 64 + (c ^ (r & 7)) * 8];
      }
      #pragma unroll
      for (int m = 0; m < 4; ++m)
        #pragma unroll
        for (int n = 0; n < 4; ++n)
          acc[m][n] = __builtin_amdgcn_mfma_f32_16x16x32_bf16(
              af[m], bfr[n], acc[m][n], 0, 0, 0);
    }
    __syncthreads();
  }
}

// ---------- fused 5-way projection (MFMA): out[z] = x . W[z]^T ---------------
__global__ __launch_bounds__(256) void proj5_mfma(
    const ushort_t* __restrict__ xb, const ushort_t* __restrict__ wb,
    ushort_t* __restrict__ qh_b, ushort_t* __restrict__ kh_b,
    ushort_t* __restrict__ dt0, ushort_t* __restrict__ vt_b) {
  __shared__ ushort_t ldsA[128 * 64];
  __shared__ ushort_t ldsB[128 * 64];
  int tid = threadIdx.x;
  int orig = (blockIdx.x & 7) * 80 + (blockIdx.x >> 3);
  int bx = orig & 7, by = (orig >> 3) & 15, z = orig >> 7;
  const ushort_t* W = wb + (size_t)z * (DM * DM);
  f32x4 acc[4][4];
  #pragma unroll
  for (int m = 0; m < 4; ++m)
    #pragma unroll
    for (int n = 0; n < 4; ++n) acc[m][n] = (f32x4){0.f, 0.f, 0.f, 0.f};
  gemm_core<DM>(xb + (size_t)by * 128 * DM,
                W + (size_t)bx * 128 * DM, ldsA, ldsB, tid, acc);
  const int lane = tid & 63, wid = tid >> 6;
  int row0 = by * 128 + (wid >> 1) * 64 + (lane >> 4) * 4;
  int col0 = bx * 128 + (wid & 1) * 64 + (lane & 15);
  #pragma unroll
  for (int m = 0; m < 4; ++m)
    #pragma unroll
    for (int n = 0; n < 4; ++n)
      #pragma unroll
      for (int j = 0; j < 4; ++j) {
        int nr = row0 + m * 16 + j;
        int mc = col0 + n * 16;
        int b = nr >> 10, t = nr & 1023, h = mc >> 6, d = mc & 63;
        int head = b * H_ + h;
        float v = acc[m][n][j];
        if (z == 0) {
          qh_b[((size_t)head * T_ + t) * DK_ + d] = f2bf(v);
        } else if (z == 1) {
          kh_b[((size_t)head * T_ + t) * DK_ + d] = f2bf(v);
        } else if (z == 4) {
          vt_b[(size_t)head * 65536 + (size_t)d * 1024 + t] = f2bf(v);
        } else {
          int ddofs = (z == 3) ? 64 : 0;
          dt0[(size_t)head * 131072 + (size_t)(d + ddofs) * 1024 + t] = f2bf(v);
        }
      }
}

// ---------- batched NT MFMA GEMM -> scaled bf16 dense (adjacency) -----------
template<int KDIM>
__global__ __launch_bounds__(256) void score_mfma(
    const ushort_t* __restrict__ A, const ushort_t* __restrict__ Bm,
    ushort_t* __restrict__ Sout, float scale) {
  __shared__ ushort_t ldsA[128 * 64];
  __shared__ ushort_t ldsB[128 * 64];
  int tid = threadIdx.x;
  int orig = (blockIdx.x & 7) * 256 + (blockIdx.x >> 3);
  int bx = orig & 7, by = (orig >> 3) & 7, z = orig >> 6;
  f32x4 acc[4][4];
  #pragma unroll
  for (int m = 0; m < 4; ++m)
    #pragma unroll
    for (int n = 0; n < 4; ++n) acc[m][n] = (f32x4){0.f, 0.f, 0.f, 0.f};
  gemm_core<KDIM>(A + (size_t)z * T_ * KDIM + (size_t)by * 128 * KDIM,
                  Bm + (size_t)z * T_ * KDIM + (size_t)bx * 128 * KDIM,
                  ldsA, ldsB, tid, acc);
  const int lane = tid & 63, wid = tid >> 6;
  int row0 = by * 128 + (wid >> 1) * 64 + (lane >> 4) * 4;
  int col0 = bx * 128 + (wid & 1) * 64 + (lane & 15);
  ushort_t* Sz = Sout + (size_t)z * T_ * T_;
  #pragma unroll
  for (int m = 0; m < 4; ++m)
    #pragma unroll
    for (int n = 0; n < 4; ++n)
      #pragma unroll
      for (int j = 0; j < 4; ++j)
        Sz[(size_t)(row0 + m * 16 + j) * T_ + col0 + n * 16] =
            f2bf(acc[m][n][j] * scale);
}

// ---------- symmetric phase score: S = scale * P P^T (upper triangle) -------
__global__ __launch_bounds__(256) void score_sym_mfma(
    const ushort_t* __restrict__ P, ushort_t* __restrict__ Sout, float scale) {
  __shared__ ushort_t lds[128 * 128];  // 32 KB; first 16 KB=A, next 16 KB=B
  ushort_t* ldsA = lds;
  ushort_t* ldsB = lds + 128 * 64;
  int tid = threadIdx.x;
  int swz = (blockIdx.x & 7) * 144 + (blockIdx.x >> 3);  // 1152 = 8*144
  int z = swz / 36, t = swz % 36;
  int by = 0, rem = t;
  while (rem >= 8 - by) { rem -= 8 - by; ++by; }
  int bx = by + rem;
  const ushort_t* Pz = P + (size_t)z * T_ * 128;
  f32x4 acc[4][4];
  #pragma unroll
  for (int m = 0; m < 4; ++m)
    #pragma unroll
    for (int n = 0; n < 4; ++n) acc[m][n] = (f32x4){0.f, 0.f, 0.f, 0.f};
  gemm_core<128>(Pz + (size_t)by * 128 * 128, Pz + (size_t)bx * 128 * 128,
                 ldsA, ldsB, tid, acc);
  const int lane = tid & 63, wid = tid >> 6;
  const int l15 = lane & 15, l4 = lane >> 4;
  ushort_t* Sz = Sout + (size_t)z * T_ * T_;
  int row0 = by * 128 + (wid >> 1) * 64 + l4 * 4;
  int col0 = bx * 128 + (wid & 1) * 64 + l15;
  #pragma unroll
  for (int m = 0; m < 4; ++m)
    #pragma unroll
    for (int n = 0; n < 4; ++n)
      #pragma unroll
      for (int j = 0; j < 4; ++j)
        Sz[(size_t)(row0 + m * 16 + j) * T_ + col0 + n * 16] =
            f2bf(acc[m][n][j] * scale);
  if (bx != by) {
    int lr0 = (wid >> 1) * 64 + l4 * 4;
    int lc0 = (wid & 1) * 64 + l15;
    #pragma unroll
    for (int m = 0; m < 4; ++m)
      #pragma unroll
      for (int n = 0; n < 4; ++n)
        #pragma unroll
        for (int j = 0; j < 4; ++j) {
          int lr = lr0 + m * 16 + j;
          int lc = lc0 + n * 16;
          lds[lc * 128 + (lr ^ ((lc & 15) << 3))] = f2bf(acc[m][n][j] * scale);
        }
    __syncthreads();
    int p = tid >> 1, qh = (tid & 1) * 64;
    int s = (p & 15) << 3;
    ushort_t* dstRow = Sz + (size_t)(bx * 128 + p) * T_ + by * 128 + qh;
    #pragma unroll
    for (int qc = 0; qc < 8; ++qc)
      *(u16x8*)&dstRow[qc * 8] =
          *(const u16x8*)&lds[p * 128 + ((qh + qc * 8) ^ s)];
  }
}

// ---------- shared BM=64 x BN=128 x K=1024 MFMA loop -------------------------
__device__ __forceinline__ void mfma_64x128_loop(
    const ushort_t* __restrict__ Ah, const ushort_t* __restrict__ Bh,
    ushort_t* ldsA, ushort_t* ldsB, int tid, f32x4 acc[2][4]) {
  const int lane = tid & 63, wid = tid >> 6;
  const int wr = wid >> 1, wc = wid & 1;
  const int l15 = lane & 15, l4 = lane >> 4;
  for (int k0 = 0; k0 < 1024; k0 += 64) {
    #pragma unroll
    for (int i = 0; i < 2; ++i) {       // A: 512 chunks of 16B
      int cid = tid + 256 * i;
      int rowc = cid >> 3, slot = cid & 7;
      int gc = slot ^ (rowc & 7);
      gload_lds16(&Ah[(size_t)rowc * 1024 + k0 + gc * 8], &ldsA[cid * 8]);
    }
    #pragma unroll
    for (int i = 0; i < 4; ++i) {       // B: 1024 chunks of 16B
      int cid = tid + 256 * i;
      int rowc = cid >> 3, slot = cid & 7;
      int gc = slot ^ (rowc & 7);
      gload_lds16(&Bh[(size_t)rowc * 1024 + k0 + gc * 8], &ldsB[cid * 8]);
    }
    __syncthreads();
    #pragma unroll
    for (int ks = 0; ks < 2; ++ks) {
      short8 af[2], bfr[4];
      #pragma unroll
      for (int m = 0; m < 2; ++m) {
        int r = wr * 32 + m * 16 + l15;
        int c = ks * 4 + l4;
        af[m] = *(const short8*)&ldsA[r * 64 + (c ^ (r & 7)) * 8];
      }
      #pragma unroll
      for (int n = 0; n < 4; ++n) {
        int r = wc * 64 + n * 16 + l15;
        int c = ks * 4 + l4;
        bfr[n] = *(const short8*)&ldsB[r * 64 + (c ^ (r & 7)) * 8];
      }
      #pragma unroll
      for (int m = 0; m < 2; ++m)
        #pragma unroll
        for (int n = 0; n < 4; ++n)
          acc[m][n] = __builtin_amdgcn_mfma_f32_16x16x32_bf16(
              af[m], bfr[n], acc[m][n], 0, 0, 0);
    }
    __syncthreads();
  }
}

// ---------------------------------------------------------------------------
// Wave-level exact top-128 + softmax for ONE row (bf16 scores in v0/v1,
// element s = g*512 + lane*8 + e). Ballot binary-search threshold, exact
// lower-index tie-break. Writes fp32 weights (if denseRow) and/or bf16
// weights (if wRow). Call sites pass compile-time-null pointers -> folded.
// ---------------------------------------------------------------------------
__device__ __forceinline__ void topk_row(
    u16x8 v0, u16x8 v1, int lane,
    float* __restrict__ denseRow, ushort_t* __restrict__ wRow) {
  float scr[2][8];
  unsigned kk[2][8];
  #pragma unroll
  for (int e = 0; e < 8; ++e) {
    scr[0][e] = bf2f(v0[e]); kk[0][e] = fkey16((unsigned)v0[e]);
    scr[1][e] = bf2f(v1[e]); kk[1][e] = fkey16((unsigned)v1[e]);
  }
  unsigned prefix = 0, r = TOPK;
  #pragma unroll
  for (int b = 15; b >= 0; --b) {
    unsigned want = (prefix << 1) | 1u;
    unsigned cnt = 0;
    #pragma unroll
    for (int g = 0; g < 2; ++g)
      #pragma unroll
      for (int e = 0; e < 8; ++e)
        cnt += (unsigned)__popcll(__ballot((kk[g][e] >> b) == want));
    if (cnt >= r) prefix = want;
    else { prefix <<= 1; r -= cnt; }
  }
  const unsigned thr = prefix;

  float mx = -3.402823466e38f;
  #pragma unroll
  for (int g = 0; g < 2; ++g)
    #pragma unroll
    for (int e = 0; e < 8; ++e) mx = fmaxf(mx, scr[g][e]);
  #pragma unroll
  for (int off = 1; off < 64; off <<= 1) mx = fmaxf(mx, __shfl_xor(mx, off));

  const unsigned long long below = (1ull << lane) - 1ull;
  unsigned cum = 0;
  float w[2][8];
  float ps = 0.f;
  #pragma unroll
  for (int g = 0; g < 2; ++g) {
    unsigned long long bal[8];
    #pragma unroll
    for (int e = 0; e < 8; ++e) bal[e] = __ballot(kk[g][e] == thr);
    unsigned rb = cum;
    #pragma unroll
    for (int e = 0; e < 8; ++e) rb += (unsigned)__popcll(bal[e] & below);
    unsigned ownPrior = 0;
    #pragma unroll
    for (int e = 0; e < 8; ++e) {
      bool eq = (kk[g][e] == thr);
      bool sel = (kk[g][e] > thr) || (eq && (rb + ownPrior) < r);
      ownPrior += eq ? 1u : 0u;
      float ex = sel ? __expf(scr[g][e] - mx) : 0.f;
      w[g][e] = ex;
      ps += ex;
    }
    #pragma unroll
    for (int e = 0; e < 8; ++e) cum += (unsigned)__popcll(bal[e]);
  }
  float pss = ps;
  #pragma unroll
  for (int off = 1; off < 64; off <<= 1) pss += __shfl_xor(pss, off);
  const float inv = 1.f / pss;

  if (denseRow) {
    #pragma unroll
    for (int g = 0; g < 2; ++g) {
      *(float4*)&denseRow[g * 512 + lane * 8] =
          make_float4(w[g][0] * inv, w[g][1] * inv, w[g][2] * inv, w[g][3] * inv);
      *(float4*)&denseRow[g * 512 + lane * 8 + 4] =
          make_float4(w[g][4] * inv, w[g][5] * inv, w[g][6] * inv, w[g][7] * inv);
    }
  }
  if (wRow) {
    #pragma unroll
    for (int g = 0; g < 2; ++g) {
      u16x8 o;
      #pragma unroll
      for (int e = 0; e < 8; ++e) o[e] = f2bf(w[g][e] * inv);
      *(u16x8*)&wRow[g * 512 + lane * 8] = o;
    }
  }
}

// ---------------------------------------------------------------------------
// FUSED adjacency topk + prop step 1. Block = (bx t-tile, hz head); each of
// 4 waves top-k's 16 of the block's 64 score rows (Sc, dense scratch) and
// writes bf16 weights to Ab (different buffer: write->read is L1-safe).
// Then the standard prop MFMA consumes the just-written, L2-hot weights.
// ---------------------------------------------------------------------------
__global__ __launch_bounds__(256) void topk_prop1_mfma(
    const ushort_t* __restrict__ Sc, ushort_t* __restrict__ Ab,
    const ushort_t* __restrict__ Dsrc, ushort_t* __restrict__ Ddst,
    const float* __restrict__ logit_lam) {
  __shared__ ushort_t ldsA[64 * 64];
  __shared__ ushort_t ldsB[128 * 64];
  int tid = threadIdx.x;
  int orig = (blockIdx.x & 7) * 64 + (blockIdx.x >> 3);
  int bx = orig & 15, hz = orig >> 4;
  const int lane = tid & 63, wid = tid >> 6;
  const size_t baseRow = (size_t)hz * 1024 + (size_t)bx * 64;
  // phase 1: top-k + softmax on this block's 64 rows (prefetch depth 1)
  {
    const ushort_t* sr = Sc + (baseRow + wid * 16) * 1024;
    ushort_t* wrp = Ab + (baseRow + wid * 16) * 1024;
    u16x8 c0 = *(const u16x8*)&sr[lane * 8];
    u16x8 c1 = *(const u16x8*)&sr[512 + lane * 8];
    for (int rr = 0; rr < 16; ++rr) {
      u16x8 n0, n1;
      if (rr < 15) {
        n0 = *(const u16x8*)&sr[(size_t)(rr + 1) * 1024 + lane * 8];
        n1 = *(const u16x8*)&sr[(size_t)(rr + 1) * 1024 + 512 + lane * 8];
      }
      topk_row(c0, c1, lane, nullptr, wrp + (size_t)rr * 1024);
      if (rr < 15) { c0 = n0; c1 = n1; }
    }
  }
  __syncthreads();
  // phase 2: prop MFMA on own weights (L2-hot)
  const int wr = wid >> 1, wc = wid & 1;
  const int l15 = lane & 15, l4 = lane >> 4;
  const ushort_t* Dh = Dsrc + (size_t)hz * 131072;
  f32x4 acc[2][4];
  #pragma unroll
  for (int m = 0; m < 2; ++m)
    #pragma unroll
    for (int n = 0; n < 4; ++n) acc[m][n] = (f32x4){0.f, 0.f, 0.f, 0.f};
  mfma_64x128_loop(Ab + baseRow * 1024, Dh, ldsA, ldsB, tid, acc);
  float lam = 1.f / (1.f + __expf(-logit_lam[0]));
  ushort_t* Dd = Ddst + (size_t)hz * 131072;
  #pragma unroll
  for (int m = 0; m < 2; ++m)
    #pragma unroll
    for (int n = 0; n < 4; ++n)
      #pragma unroll
      for (int j = 0; j < 4; ++j) {
        int t = bx * 64 + wr * 32 + m * 16 + l4 * 4 + j;
        int dd = wc * 64 + n * 16 + l15;
        size_t o = (size_t)dd * 1024 + t;
        float oldv = bf2f(Dh[o]);
        Dd[o] = f2bf((1.f - lam) * oldv + lam * acc[m][n][j]);
      }
}

// ---------- propagation step (per head), BM=64, 1D grid 512, XCD-swizzled ---
__global__ __launch_bounds__(256) void prop_mfma(
    const ushort_t* __restrict__ Ab, const ushort_t* __restrict__ Dsrc,
    ushort_t* __restrict__ Ddst, const float* __restrict__ logit_lam) {
  __shared__ ushort_t ldsA[64 * 64];
  __shared__ ushort_t ldsB[128 * 64];
  int tid = threadIdx.x;
  int orig = (blockIdx.x & 7) * 64 + (blockIdx.x >> 3);
  int bx = orig & 15, hz = orig >> 4;
  const int lane = tid & 63, wid = tid >> 6;
  const int wr = wid >> 1, wc = wid & 1;
  const int l15 = lane & 15, l4 = lane >> 4;
  const ushort_t* Dh = Dsrc + (size_t)hz * 131072;
  f32x4 acc[2][4];
  #pragma unroll
  for (int m = 0; m < 2; ++m)
    #pragma unroll
    for (int n = 0; n < 4; ++n) acc[m][n] = (f32x4){0.f, 0.f, 0.f, 0.f};
  mfma_64x128_loop(Ab + (size_t)hz * 1048576 + (size_t)bx * 64 * 1024,
                   Dh, ldsA, ldsB, tid, acc);
  float lam = 1.f / (1.f + __expf(-logit_lam[0]));
  ushort_t* Dd = Ddst + (size_t)hz * 131072;
  #pragma unroll
  for (int m = 0; m < 2; ++m)
    #pragma unroll
    for (int n = 0; n < 4; ++n)
      #pragma unroll
      for (int j = 0; j < 4; ++j) {
        int t = bx * 64 + wr * 32 + m * 16 + l4 * 4 + j;
        int dd = wc * 64 + n * 16 + l15;
        size_t o = (size_t)dd * 1024 + t;
        float oldv = bf2f(Dh[o]);
        Dd[o] = f2bf((1.f - lam) * oldv + lam * acc[m][n][j]);
      }
}

// ---------- final prop step fused with finalize: blend + alpha*D0 + norm ----
__global__ __launch_bounds__(256) void prop_final_mfma(
    const ushort_t* __restrict__ Ab, const ushort_t* __restrict__ Dsrc,
    const ushort_t* __restrict__ Dt0, ushort_t* __restrict__ P,
    const float* __restrict__ logit_lam, const float* __restrict__ log_alpha) {
  __shared__ ushort_t ldsA[64 * 64];
  __shared__ ushort_t ldsB[128 * 64];
  __shared__ float sums[4][2][4][4];   // [wid][m][j][l4]
  int tid = threadIdx.x;
  int orig = (blockIdx.x & 7) * 64 + (blockIdx.x >> 3);
  int bx = orig & 15, hz = orig >> 4;
  const int lane = tid & 63, wid = tid >> 6;
  const int wr = wid >> 1, wc = wid & 1;
  const int l15 = lane & 15, l4 = lane >> 4;
  const ushort_t* Dh = Dsrc + (size_t)hz * 131072;
  f32x4 acc[2][4];
  #pragma unroll
  for (int m = 0; m < 2; ++m)
    #pragma unroll
    for (int n = 0; n < 4; ++n) acc[m][n] = (f32x4){0.f, 0.f, 0.f, 0.f};
  mfma_64x128_loop(Ab + (size_t)hz * 1048576 + (size_t)bx * 64 * 1024,
                   Dh, ldsA, ldsB, tid, acc);
  float lam = 1.f / (1.f + __expf(-logit_lam[0]));
  float alpha = 1.f / (1.f + __expf(-log_alpha[0]));
  const ushort_t* D0h = Dt0 + (size_t)hz * 131072;
  float F[2][4][4];
  float ssp[2][4];
  #pragma unroll
  for (int m = 0; m < 2; ++m)
    #pragma unroll
    for (int j = 0; j < 4; ++j) {
      int t = bx * 64 + wr * 32 + m * 16 + l4 * 4 + j;
      float s = 0.f;
      #pragma unroll
      for (int n = 0; n < 4; ++n) {
        int dd = wc * 64 + n * 16 + l15;
        size_t o = (size_t)dd * 1024 + t;
        float f = (1.f - lam) * bf2f(Dh[o]) + lam * acc[m][n][j] +
                  alpha * bf2f(D0h[o]);
        F[m][n][j] = f;
        s += f * f;
      }
      #pragma unroll
      for (int off = 1; off < 16; off <<= 1) s += __shfl_xor(s, off);
      ssp[m][j] = s;
    }
  if (l15 == 0) {
    #pragma unroll
    for (int m = 0; m < 2; ++m)
      #pragma unroll
      for (int j = 0; j < 4; ++j)
        sums[wid][m][j][l4] = ssp[m][j];
  }
  __syncthreads();
  ushort_t* Ph = P + (size_t)hz * 1024 * 128;
  #pragma unroll
  for (int m = 0; m < 2; ++m)
    #pragma unroll
    for (int j = 0; j < 4; ++j) {
      float tot = sums[wid][m][j][l4] + sums[wid ^ 1][m][j][l4];
      float ni = 1.f / fmaxf(sqrtf(tot), 1e-6f);
      int t = bx * 64 + wr * 32 + m * 16 + l4 * 4 + j;
      #pragma unroll
      for (int n = 0; n < 4; ++n) {
        int dd = wc * 64 + n * 16 + l15;
        Ph[(size_t)t * 128 + dd] = f2bf(F[m][n][j] * ni);
      }
    }
}

// ---------------------------------------------------------------------------
// FUSED phase topk + attn.V. Block = (bx t-tile, hz head); waves top-k the
// block's 64 score rows (S2_b) writing the fp32 phase_attn output rows, then
// the attnv MFMA consumes those same rows (own-XCD L2 hot) with reg-staged
// fp32->bf16 conversion (bitwise-identical to the old bf16 writeback path).
// ---------------------------------------------------------------------------
__global__ __launch_bounds__(256) void topk_attnv_mfma(
    const ushort_t* __restrict__ Sc, float* __restrict__ dense,
    const ushort_t* __restrict__ Vt, ushort_t* __restrict__ attn_b) {
  __shared__ ushort_t ldsA[64 * 64];   // A: weights bf16 (8 KB)
  __shared__ ushort_t ldsB[64 * 64];   // B: V (8 KB)
  int tid = threadIdx.x;
  int orig = (blockIdx.x & 7) * 64 + (blockIdx.x >> 3);
  int bx = orig & 15, hz = orig >> 4;
  const int lane = tid & 63, wid = tid >> 6;
  const size_t baseRow = (size_t)hz * 1024 + (size_t)bx * 64;
  // phase 1: top-k + softmax -> fp32 dense output rows
  {
    const ushort_t* sr = Sc + (baseRow + wid * 16) * 1024;
    float* dr = dense + (baseRow + wid * 16) * 1024;
    u16x8 c0 = *(const u16x8*)&sr[lane * 8];
    u16x8 c1 = *(const u16x8*)&sr[512 + lane * 8];
    for (int rr = 0; rr < 16; ++rr) {
      u16x8 n0, n1;
      if (rr < 15) {
        n0 = *(const u16x8*)&sr[(size_t)(rr + 1) * 1024 + lane * 8];
        n1 = *(const u16x8*)&sr[(size_t)(rr + 1) * 1024 + 512 + lane * 8];
      }
      topk_row(c0, c1, lane, dr + (size_t)rr * 1024, nullptr);
      if (rr < 15) { c0 = n0; c1 = n1; }
    }
  }
  __syncthreads();
  // phase 2: attn.V MFMA from own fp32 rows
  const int wr = wid >> 1, wc = wid & 1;
  const int l15 = lane & 15, l4 = lane >> 4;
  const float* Wh = dense + baseRow * 1024;
  const ushort_t* Vh = Vt + (size_t)hz * 65536;
  f32x4 acc[2][2];
  #pragma unroll
  for (int m = 0; m < 2; ++m)
    #pragma unroll
    for (int n = 0; n < 2; ++n) acc[m][n] = (f32x4){0.f, 0.f, 0.f, 0.f};
  for (int k0 = 0; k0 < 1024; k0 += 64) {
    #pragma unroll
    for (int i = 0; i < 4; ++i) {       // A: 1024 fp32-16B chunks -> bf16
      int cid = tid + 256 * i;
      int rowc = cid >> 4, c4 = cid & 15;
      float4 v = *(const float4*)&Wh[(size_t)rowc * 1024 + k0 + c4 * 4];
      int c = c4 >> 1, half = c4 & 1;
      ushort4 o;
      o.x = f2bf(v.x); o.y = f2bf(v.y); o.z = f2bf(v.z); o.w = f2bf(v.w);
      *(ushort4*)&ldsA[rowc * 64 + (c ^ (rowc & 7)) * 8 + half * 4] = o;
    }
    #pragma unroll
    for (int i = 0; i < 2; ++i) {       // B: 512 bf16-16B chunks
      int cid = tid + 256 * i;
      int rowc = cid >> 3, slot = cid & 7;
      int gc = slot ^ (rowc & 7);
      gload_lds16(&Vh[(size_t)rowc * 1024 + k0 + gc * 8], &ldsB[cid * 8]);
    }
    __syncthreads();
    #pragma unroll
    for (int ks = 0; ks < 2; ++ks) {
      short8 af[2], bfr[2];
      #pragma unroll
      for (int m = 0; m < 2; ++m) {
        int r = wr * 32 + m * 16 + l15;
        int c = ks * 4 + l4;
        af[m] = *(const short8*)&ldsA[r * 64 + (c ^ (r & 7)) * 8];
      }
      #pragma unroll
      for (int n = 0; n < 2; ++n) {
        int r = wc * 32 + n * 16 + l15;
        int c = ks * 4 + l4;
        bfr[n] = *(const short8*)&ldsB[r * 64 + (c ^ (r & 7)) * 8];
      }
      #pragma unroll
      for (int m = 0; m < 2; ++m)
        #pragma unroll
        for (int n = 0; n < 2; ++n)
          acc[m][n] = __builtin_amdgcn_mfma_f32_16x16x32_bf16(
              af[m], bfr[n], acc[m][n], 0, 0, 0);
    }
    __syncthreads();
  }
  int b = hz >> 4, h = hz & 15;
  #pragma unroll
  for (int m = 0; m < 2; ++m)
    #pragma unroll
    for (int n = 0; n < 2; ++n)
      #pragma unroll
      for (int j = 0; j < 4; ++j) {
        int t = bx * 64 + wr * 32 + m * 16 + l4 * 4 + j;
        int d = wc * 32 + n * 16 + l15;
        attn_b[((size_t)(b * T_ + t)) * DM + h * DK_ + d] = f2bf(acc[m][n][j]);
      }
}

// ---------- output projection: BM=64 x BN=128 x K=1024, grid 256 ------------
__global__ __launch_bounds__(256) void outproj_mfma(
    const ushort_t* __restrict__ A, const ushort_t* __restrict__ Wo,
    float* __restrict__ out) {
  __shared__ ushort_t ldsA[64 * 64];
  __shared__ ushort_t ldsB[128 * 64];
  int tid = threadIdx.x;
  int orig = (blockIdx.x & 7) * 32 + (blockIdx.x >> 3);
  int bx = orig & 7, by = orig >> 3;   // bx: 128-col tile, by: 64-row tile
  const int lane = tid & 63, wid = tid >> 6;
  const int wr = wid >> 1, wc = wid & 1;
  const int l15 = lane & 15, l4 = lane >> 4;
  f32x4 acc[2][4];
  #pragma unroll
  for (int m = 0; m < 2; ++m)
    #pragma unroll
    for (int n = 0; n < 4; ++n) acc[m][n] = (f32x4){0.f, 0.f, 0.f, 0.f};
  mfma_64x128_loop(A + (size_t)by * 64 * 1024,
                   Wo + (size_t)bx * 128 * 1024, ldsA, ldsB, tid, acc);
  #pragma unroll
  for (int m = 0; m < 2; ++m)
    #pragma unroll
    for (int n = 0; n < 4; ++n)
      #pragma unroll
      for (int j = 0; j < 4; ++j) {
        int r = by * 64 + wr * 32 + m * 16 + l4 * 4 + j;
        int c = bx * 128 + wc * 64 + n * 16 + l15;
        out[(size_t)r * 1024 + c] = acc[m][n][j];
      }
}

extern "C" void kernel_launch(void* const* d_in, const int* in_sizes, int n_in,
                              void* d_out, int out_size, void* d_ws, size_t ws_size,
                              hipStream_t stream) {
  (void)in_sizes; (void)n_in; (void)out_size; (void)ws_size;
  const float* x         = (const float*)d_in[0];
  const float* wq        = (const float*)d_in[1];
  const float* wk        = (const float*)d_in[2];
  const float* wre       = (const float*)d_in[3];
  const float* wim       = (const float*)d_in[4];
  const float* wv        = (const float*)d_in[5];
  const float* wo        = (const float*)d_in[6];
  const float* logit_lam = (const float*)d_in[7];
  const float* log_alpha = (const float*)d_in[8];

  float* out   = (float*)d_out;                 // (B,T,DM)
  float* dense = out + (size_t)B_ * T_ * DM;    // phase_attn (B,H,T,T) fp32 out
  // dense region timeline: bf16 weight scratch (cast6->proj5) -> adjacency
  // bf16 scores (score_mfma -> topk_prop1) -> fp32 phase weights (final out).
  ushort_t* w5_b   = (ushort_t*)dense;
  ushort_t* sc_adj = (ushort_t*)dense;          // adjacency scores, 64 MB

  char* ws = (char*)d_ws;
  const size_t MB = (size_t)1 << 20;
  // ws 0-64 MB: adjacency bf16 WEIGHTS (prop input); then phase bf16 scores.
  ushort_t* A_b  = (ushort_t*)(ws + 0 * MB);
  ushort_t* S2_b = A_b;                          // phase scores (A dead)
  ushort_t* dt0  = (ushort_t*)(ws + 64 * MB);    // 8 MB Dt0 [32][128][1024]
  ushort_t* dtA  = (ushort_t*)(ws + 72 * MB);    // 8 MB ping
  ushort_t* dtB  = (ushort_t*)(ws + 80 * MB);    // 8 MB pong; P_b after prop3
  ushort_t* P_b  = dtB;                          // packed [t][Ur|Ui] bf16
  ushort_t* vt_b = (ushort_t*)(ws + 88 * MB);    // 4 MB Vt [32][64][1024]
  ushort_t* xb   = (ushort_t*)(ws + 92 * MB);    // 4 MB bf16 x; reused attn_b
  ushort_t* attn_b = xb;                         // alias (x dead after proj)
  ushort_t* qh_b = (ushort_t*)(ws + 96 * MB);    // 4 MB bf16 Q; wo_b after adj
  ushort_t* wo_b = qh_b;                         // alias (Q dead after scores)
  ushort_t* kh_b = (ushort_t*)(ws + 100 * MB);   // 4 MB bf16 K
  // total workspace: 104 MB

  // 0. bf16 casts, one launch (W_O deferred until Q is dead)
  cast6_kernel<<<dim3(2048, 6), 256, 0, stream>>>(
      x, wq, wk, wre, wim, wv, xb, w5_b);

  // 1. all 5 projections (MFMA)
  proj5_mfma<<<640, 256, 0, stream>>>(xb, w5_b, qh_b, kh_b, dt0, vt_b);

  // 2. adjacency scores -> dense scratch (w5_b region, dead after proj5)
  score_mfma<64><<<2048, 256, 0, stream>>>(qh_b, kh_b, sc_adj, 0.125f);
  cast_bf16_kernel<<<1024, 256, 0, stream>>>(wo, wo_b, DM * DM / 4);  // Q dead

  // 3. FUSED adjacency topk (-> A_b weights) + prop step 1; then steps 2,3
  //    and final step fused with finalize -> P_b
  topk_prop1_mfma<<<512, 256, 0, stream>>>(sc_adj, A_b, dt0, dtA, logit_lam);
  prop_mfma<<<512, 256, 0, stream>>>(A_b, dtA, dtB, logit_lam);
  prop_mfma<<<512, 256, 0, stream>>>(A_b, dtB, dtA, logit_lam);
  prop_final_mfma<<<512, 256, 0, stream>>>(A_b, dtA, dt0, P_b,
                                           logit_lam, log_alpha);

  // 4. phase scores, symmetric (bf16 -> S2_b over dead A weights)
  score_sym_mfma<<<1152, 256, 0, stream>>>(P_b, S2_b, 11.3137085f);

  // 5. FUSED phase topk (-> fp32 dense output) + attn.V; then out projection
  topk_attnv_mfma<<<512, 256, 0, stream>>>(S2_b, dense, vt_b, attn_b);
  outproj_mfma<<<256, 256, 0, stream>>>(attn_b, wo_b, out);
}

// Round 14
// 339.929 us; speedup vs baseline: 1.1838x; 1.1838x over previous
//
#include <hip/hip_runtime.h>
#include <cstdint>
#include <cstddef>

// Problem constants
#define B_  2
#define T_  1024
#define DM  1024
#define H_  16
#define DK_ 64
#define TOPK 128

typedef unsigned short ushort_t;
typedef __attribute__((ext_vector_type(8))) short short8;
typedef __attribute__((ext_vector_type(8))) unsigned short u16x8;
typedef __attribute__((ext_vector_type(4))) float f32x4;

// monotone map bf16 bits -> u16 (bigger key == bigger float)
__device__ __forceinline__ unsigned fkey16(unsigned b) {
  return (b & 0x8000u) ? (0xffffu & ~b) : (b | 0x8000u);
}

// round-to-nearest-even float -> bf16
__device__ __forceinline__ ushort_t f2bf(float f) {
  unsigned u = __float_as_uint(f);
  return (ushort_t)((u + 0x7fffu + ((u >> 16) & 1u)) >> 16);
}
__device__ __forceinline__ float bf2f(ushort_t u) {
  return __uint_as_float((unsigned)u << 16);
}

// async global->LDS 16B copy (linear LDS dest; global src may be swizzled)
__device__ __forceinline__ void gload_lds16(const ushort_t* g, ushort_t* l) {
  __builtin_amdgcn_global_load_lds(
      (const __attribute__((address_space(1))) unsigned int*)(const void*)g,
      (__attribute__((address_space(3))) unsigned int*)(void*)l, 16, 0, 0);
}

// ---------- fused bf16 casts: x + 5 weights in one launch --------------------
__global__ __launch_bounds__(256) void cast6_kernel(
    const float* __restrict__ x, const float* __restrict__ wq,
    const float* __restrict__ wk, const float* __restrict__ wre,
    const float* __restrict__ wim, const float* __restrict__ wv,
    ushort_t* __restrict__ xb, ushort_t* __restrict__ w5b) {
  int z = blockIdx.y;
  const float* src; ushort_t* dst; int n4;
  switch (z) {
    case 0: src = x;   dst = xb;                 n4 = 524288; break;
    case 1: src = wq;  dst = w5b;                n4 = 262144; break;
    case 2: src = wk;  dst = w5b + 1048576;      n4 = 262144; break;
    case 3: src = wre; dst = w5b + 2097152;      n4 = 262144; break;
    case 4: src = wim; dst = w5b + 3145728;      n4 = 262144; break;
    default: src = wv; dst = w5b + 4194304;      n4 = 262144; break;
  }
  int i = blockIdx.x * 256 + threadIdx.x;
  if (i < n4) {
    float4 v = ((const float4*)src)[i];
    ushort4 o;
    o.x = f2bf(v.x); o.y = f2bf(v.y); o.z = f2bf(v.z); o.w = f2bf(v.w);
    ((ushort4*)dst)[i] = o;
  }
}

__global__ __launch_bounds__(256) void cast_bf16_kernel(
    const float* __restrict__ in, ushort_t* __restrict__ out, int n4) {
  int i = blockIdx.x * 256 + threadIdx.x;
  if (i < n4) {
    float4 v = ((const float4*)in)[i];
    ushort4 o;
    o.x = f2bf(v.x); o.y = f2bf(v.y); o.z = f2bf(v.z); o.w = f2bf(v.w);
    ((ushort4*)out)[i] = o;
  }
}

// ---------------------------------------------------------------------------
// bf16 MFMA NT GEMM core: 128x128 tile, BK=64, 4 waves (2x2), fp32 acc.
// ---------------------------------------------------------------------------
template<int KDIM>
__device__ __forceinline__ void gemm_core(
    const ushort_t* __restrict__ Ab, const ushort_t* __restrict__ Bb,
    ushort_t* ldsA, ushort_t* ldsB, int tid, f32x4 acc[4][4]) {
  const int lane = tid & 63, wid = tid >> 6;
  const int wr = (wid >> 1) * 64, wc = (wid & 1) * 64;
  const int l15 = lane & 15, l4 = lane >> 4;
  for (int k0 = 0; k0 < KDIM; k0 += 64) {
    #pragma unroll
    for (int i = 0; i < 4; ++i) {
      int cid = tid + 256 * i;          // 1024 chunks of 16B per tile
      int row = cid >> 3, slot = cid & 7;
      int gc = slot ^ (row & 7);        // pre-swizzled global chunk
      gload_lds16(&Ab[(size_t)row * KDIM + k0 + gc * 8], &ldsA[cid * 8]);
      gload_lds16(&Bb[(size_t)row * KDIM + k0 + gc * 8], &ldsB[cid * 8]);
    }
    __syncthreads();
    #pragma unroll
    for (int ks = 0; ks < 2; ++ks) {
      short8 af[4], bfr[4];
      #pragma unroll
      for (int m = 0; m < 4; ++m) {
        int r = wr + m * 16 + l15;
        int c = ks * 4 + l4;
        af[m] = *(const short8*)&ldsA[r * 64 + (c ^ (r & 7)) * 8];
      }
      #pragma unroll
      for (int n = 0; n < 4; ++n) {
        int r = wc + n * 16 + l15;
        int c = ks * 4 + l4;
        bfr[n] = *(const short8*)&ldsB[r * 64 + (c ^ (r & 7)) * 8];
      }
      #pragma unroll
      for (int m = 0; m < 4; ++m)
        #pragma unroll
        for (int n = 0; n < 4; ++n)
          acc[m][n] = __builtin_amdgcn_mfma_f32_16x16x32_bf16(
              af[m], bfr[n], acc[m][n], 0, 0, 0);
    }
    __syncthreads();
  }
}

// ---------- fused 5-way projection (MFMA): out[z] = x . W[z]^T ---------------
__global__ __launch_bounds__(256) void proj5_mfma(
    const ushort_t* __restrict__ xb, const ushort_t* __restrict__ wb,
    ushort_t* __restrict__ qh_b, ushort_t* __restrict__ kh_b,
    ushort_t* __restrict__ dt0, ushort_t* __restrict__ vt_b) {
  __shared__ ushort_t ldsA[128 * 64];
  __shared__ ushort_t ldsB[128 * 64];
  int tid = threadIdx.x;
  int orig = (blockIdx.x & 7) * 80 + (blockIdx.x >> 3);
  int bx = orig & 7, by = (orig >> 3) & 15, z = orig >> 7;
  const ushort_t* W = wb + (size_t)z * (DM * DM);
  f32x4 acc[4][4];
  #pragma unroll
  for (int m = 0; m < 4; ++m)
    #pragma unroll
    for (int n = 0; n < 4; ++n) acc[m][n] = (f32x4){0.f, 0.f, 0.f, 0.f};
  gemm_core<DM>(xb + (size_t)by * 128 * DM,
                W + (size_t)bx * 128 * DM, ldsA, ldsB, tid, acc);
  const int lane = tid & 63, wid = tid >> 6;
  int row0 = by * 128 + (wid >> 1) * 64 + (lane >> 4) * 4;
  int col0 = bx * 128 + (wid & 1) * 64 + (lane & 15);
  #pragma unroll
  for (int m = 0; m < 4; ++m)
    #pragma unroll
    for (int n = 0; n < 4; ++n)
      #pragma unroll
      for (int j = 0; j < 4; ++j) {
        int nr = row0 + m * 16 + j;
        int mc = col0 + n * 16;
        int b = nr >> 10, t = nr & 1023, h = mc >> 6, d = mc & 63;
        int head = b * H_ + h;
        float v = acc[m][n][j];
        if (z == 0) {
          qh_b[((size_t)head * T_ + t) * DK_ + d] = f2bf(v);
        } else if (z == 1) {
          kh_b[((size_t)head * T_ + t) * DK_ + d] = f2bf(v);
        } else if (z == 4) {
          vt_b[(size_t)head * 65536 + (size_t)d * 1024 + t] = f2bf(v);
        } else {
          int ddofs = (z == 3) ? 64 : 0;
          dt0[(size_t)head * 131072 + (size_t)(d + ddofs) * 1024 + t] = f2bf(v);
        }
      }
}

// ---------- batched NT MFMA GEMM -> scaled bf16 dense (adjacency) -----------
template<int KDIM>
__global__ __launch_bounds__(256) void score_mfma(
    const ushort_t* __restrict__ A, const ushort_t* __restrict__ Bm,
    ushort_t* __restrict__ Sout, float scale) {
  __shared__ ushort_t ldsA[128 * 64];
  __shared__ ushort_t ldsB[128 * 64];
  int tid = threadIdx.x;
  int orig = (blockIdx.x & 7) * 256 + (blockIdx.x >> 3);
  int bx = orig & 7, by = (orig >> 3) & 7, z = orig >> 6;
  f32x4 acc[4][4];
  #pragma unroll
  for (int m = 0; m < 4; ++m)
    #pragma unroll
    for (int n = 0; n < 4; ++n) acc[m][n] = (f32x4){0.f, 0.f, 0.f, 0.f};
  gemm_core<KDIM>(A + (size_t)z * T_ * KDIM + (size_t)by * 128 * KDIM,
                  Bm + (size_t)z * T_ * KDIM + (size_t)bx * 128 * KDIM,
                  ldsA, ldsB, tid, acc);
  const int lane = tid & 63, wid = tid >> 6;
  int row0 = by * 128 + (wid >> 1) * 64 + (lane >> 4) * 4;
  int col0 = bx * 128 + (wid & 1) * 64 + (lane & 15);
  ushort_t* Sz = Sout + (size_t)z * T_ * T_;
  #pragma unroll
  for (int m = 0; m < 4; ++m)
    #pragma unroll
    for (int n = 0; n < 4; ++n)
      #pragma unroll
      for (int j = 0; j < 4; ++j)
        Sz[(size_t)(row0 + m * 16 + j) * T_ + col0 + n * 16] =
            f2bf(acc[m][n][j] * scale);
}

// ---------- symmetric phase score: S = scale * P P^T (upper triangle) -------
__global__ __launch_bounds__(256) void score_sym_mfma(
    const ushort_t* __restrict__ P, ushort_t* __restrict__ Sout, float scale) {
  __shared__ ushort_t lds[128 * 128];  // 32 KB; first 16 KB=A, next 16 KB=B
  ushort_t* ldsA = lds;
  ushort_t* ldsB = lds + 128 * 64;
  int tid = threadIdx.x;
  int swz = (blockIdx.x & 7) * 144 + (blockIdx.x >> 3);  // 1152 = 8*144
  int z = swz / 36, t = swz % 36;
  int by = 0, rem = t;
  while (rem >= 8 - by) { rem -= 8 - by; ++by; }
  int bx = by + rem;
  const ushort_t* Pz = P + (size_t)z * T_ * 128;
  f32x4 acc[4][4];
  #pragma unroll
  for (int m = 0; m < 4; ++m)
    #pragma unroll
    for (int n = 0; n < 4; ++n) acc[m][n] = (f32x4){0.f, 0.f, 0.f, 0.f};
  gemm_core<128>(Pz + (size_t)by * 128 * 128, Pz + (size_t)bx * 128 * 128,
                 ldsA, ldsB, tid, acc);
  const int lane = tid & 63, wid = tid >> 6;
  const int l15 = lane & 15, l4 = lane >> 4;
  ushort_t* Sz = Sout + (size_t)z * T_ * T_;
  int row0 = by * 128 + (wid >> 1) * 64 + l4 * 4;
  int col0 = bx * 128 + (wid & 1) * 64 + l15;
  #pragma unroll
  for (int m = 0; m < 4; ++m)
    #pragma unroll
    for (int n = 0; n < 4; ++n)
      #pragma unroll
      for (int j = 0; j < 4; ++j)
        Sz[(size_t)(row0 + m * 16 + j) * T_ + col0 + n * 16] =
            f2bf(acc[m][n][j] * scale);
  if (bx != by) {
    int lr0 = (wid >> 1) * 64 + l4 * 4;
    int lc0 = (wid & 1) * 64 + l15;
    #pragma unroll
    for (int m = 0; m < 4; ++m)
      #pragma unroll
      for (int n = 0; n < 4; ++n)
        #pragma unroll
        for (int j = 0; j < 4; ++j) {
          int lr = lr0 + m * 16 + j;
          int lc = lc0 + n * 16;
          lds[lc * 128 + (lr ^ ((lc & 15) << 3))] = f2bf(acc[m][n][j] * scale);
        }
    __syncthreads();
    int p = tid >> 1, qh = (tid & 1) * 64;
    int s = (p & 15) << 3;
    ushort_t* dstRow = Sz + (size_t)(bx * 128 + p) * T_ + by * 128 + qh;
    #pragma unroll
    for (int qc = 0; qc < 8; ++qc)
      *(u16x8*)&dstRow[qc * 8] =
          *(const u16x8*)&lds[p * 128 + ((qh + qc * 8) ^ s)];
  }
}

// ---------- shared BM=64 x BN=128 x K=1024 MFMA loop -------------------------
__device__ __forceinline__ void mfma_64x128_loop(
    const ushort_t* __restrict__ Ah, const ushort_t* __restrict__ Bh,
    ushort_t* ldsA, ushort_t* ldsB, int tid, f32x4 acc[2][4]) {
  const int lane = tid & 63, wid = tid >> 6;
  const int wr = wid >> 1, wc = wid & 1;
  const int l15 = lane & 15, l4 = lane >> 4;
  for (int k0 = 0; k0 < 1024; k0 += 64) {
    #pragma unroll
    for (int i = 0; i < 2; ++i) {       // A: 512 chunks of 16B
      int cid = tid + 256 * i;
      int rowc = cid >> 3, slot = cid & 7;
      int gc = slot ^ (rowc & 7);
      gload_lds16(&Ah[(size_t)rowc * 1024 + k0 + gc * 8], &ldsA[cid * 8]);
    }
    #pragma unroll
    for (int i = 0; i < 4; ++i) {       // B: 1024 chunks of 16B
      int cid = tid + 256 * i;
      int rowc = cid >> 3, slot = cid & 7;
      int gc = slot ^ (rowc & 7);
      gload_lds16(&Bh[(size_t)rowc * 1024 + k0 + gc * 8], &ldsB[cid * 8]);
    }
    __syncthreads();
    #pragma unroll
    for (int ks = 0; ks < 2; ++ks) {
      short8 af[2], bfr[4];
      #pragma unroll
      for (int m = 0; m < 2; ++m) {
        int r = wr * 32 + m * 16 + l15;
        int c = ks * 4 + l4;
        af[m] = *(const short8*)&ldsA[r * 64 + (c ^ (r & 7)) * 8];
      }
      #pragma unroll
      for (int n = 0; n < 4; ++n) {
        int r = wc * 64 + n * 16 + l15;
        int c = ks * 4 + l4;
        bfr[n] = *(const short8*)&ldsB[r * 64 + (c ^ (r & 7)) * 8];
      }
      #pragma unroll
      for (int m = 0; m < 2; ++m)
        #pragma unroll
        for (int n = 0; n < 4; ++n)
          acc[m][n] = __builtin_amdgcn_mfma_f32_16x16x32_bf16(
              af[m], bfr[n], acc[m][n], 0, 0, 0);
    }
    __syncthreads();
  }
}

// ---------- propagation step (per head), BM=64, 1D grid 512, XCD-swizzled ---
__global__ __launch_bounds__(256) void prop_mfma(
    const ushort_t* __restrict__ Ab, const ushort_t* __restrict__ Dsrc,
    ushort_t* __restrict__ Ddst, const float* __restrict__ logit_lam) {
  __shared__ ushort_t ldsA[64 * 64];
  __shared__ ushort_t ldsB[128 * 64];
  int tid = threadIdx.x;
  int orig = (blockIdx.x & 7) * 64 + (blockIdx.x >> 3);
  int bx = orig & 15, hz = orig >> 4;
  const int lane = tid & 63, wid = tid >> 6;
  const int wr = wid >> 1, wc = wid & 1;
  const int l15 = lane & 15, l4 = lane >> 4;
  const ushort_t* Dh = Dsrc + (size_t)hz * 131072;
  f32x4 acc[2][4];
  #pragma unroll
  for (int m = 0; m < 2; ++m)
    #pragma unroll
    for (int n = 0; n < 4; ++n) acc[m][n] = (f32x4){0.f, 0.f, 0.f, 0.f};
  mfma_64x128_loop(Ab + (size_t)hz * 1048576 + (size_t)bx * 64 * 1024,
                   Dh, ldsA, ldsB, tid, acc);
  float lam = 1.f / (1.f + __expf(-logit_lam[0]));
  ushort_t* Dd = Ddst + (size_t)hz * 131072;
  #pragma unroll
  for (int m = 0; m < 2; ++m)
    #pragma unroll
    for (int n = 0; n < 4; ++n)
      #pragma unroll
      for (int j = 0; j < 4; ++j) {
        int t = bx * 64 + wr * 32 + m * 16 + l4 * 4 + j;
        int dd = wc * 64 + n * 16 + l15;
        size_t o = (size_t)dd * 1024 + t;
        float oldv = bf2f(Dh[o]);
        Dd[o] = f2bf((1.f - lam) * oldv + lam * acc[m][n][j]);
      }
}

// ---------- final prop step fused with finalize: blend + alpha*D0 + norm ----
__global__ __launch_bounds__(256) void prop_final_mfma(
    const ushort_t* __restrict__ Ab, const ushort_t* __restrict__ Dsrc,
    const ushort_t* __restrict__ Dt0, ushort_t* __restrict__ P,
    const float* __restrict__ logit_lam, const float* __restrict__ log_alpha) {
  __shared__ ushort_t ldsA[64 * 64];
  __shared__ ushort_t ldsB[128 * 64];
  __shared__ float sums[4][2][4][4];   // [wid][m][j][l4]
  int tid = threadIdx.x;
  int orig = (blockIdx.x & 7) * 64 + (blockIdx.x >> 3);
  int bx = orig & 15, hz = orig >> 4;
  const int lane = tid & 63, wid = tid >> 6;
  const int wr = wid >> 1, wc = wid & 1;
  const int l15 = lane & 15, l4 = lane >> 4;
  const ushort_t* Dh = Dsrc + (size_t)hz * 131072;
  f32x4 acc[2][4];
  #pragma unroll
  for (int m = 0; m < 2; ++m)
    #pragma unroll
    for (int n = 0; n < 4; ++n) acc[m][n] = (f32x4){0.f, 0.f, 0.f, 0.f};
  mfma_64x128_loop(Ab + (size_t)hz * 1048576 + (size_t)bx * 64 * 1024,
                   Dh, ldsA, ldsB, tid, acc);
  float lam = 1.f / (1.f + __expf(-logit_lam[0]));
  float alpha = 1.f / (1.f + __expf(-log_alpha[0]));
  const ushort_t* D0h = Dt0 + (size_t)hz * 131072;
  float F[2][4][4];
  float ssp[2][4];
  #pragma unroll
  for (int m = 0; m < 2; ++m)
    #pragma unroll
    for (int j = 0; j < 4; ++j) {
      int t = bx * 64 + wr * 32 + m * 16 + l4 * 4 + j;
      float s = 0.f;
      #pragma unroll
      for (int n = 0; n < 4; ++n) {
        int dd = wc * 64 + n * 16 + l15;
        size_t o = (size_t)dd * 1024 + t;
        float f = (1.f - lam) * bf2f(Dh[o]) + lam * acc[m][n][j] +
                  alpha * bf2f(D0h[o]);
        F[m][n][j] = f;
        s += f * f;
      }
      #pragma unroll
      for (int off = 1; off < 16; off <<= 1) s += __shfl_xor(s, off);
      ssp[m][j] = s;
    }
  if (l15 == 0) {
    #pragma unroll
    for (int m = 0; m < 2; ++m)
      #pragma unroll
      for (int j = 0; j < 4; ++j)
        sums[wid][m][j][l4] = ssp[m][j];
  }
  __syncthreads();
  ushort_t* Ph = P + (size_t)hz * 1024 * 128;
  #pragma unroll
  for (int m = 0; m < 2; ++m)
    #pragma unroll
    for (int j = 0; j < 4; ++j) {
      float tot = sums[wid][m][j][l4] + sums[wid ^ 1][m][j][l4];
      float ni = 1.f / fmaxf(sqrtf(tot), 1e-6f);
      int t = bx * 64 + wr * 32 + m * 16 + l4 * 4 + j;
      #pragma unroll
      for (int n = 0; n < 4; ++n) {
        int dd = wc * 64 + n * 16 + l15;
        Ph[(size_t)t * 128 + dd] = f2bf(F[m][n][j] * ni);
      }
    }
}

// ---------------------------------------------------------------------------
// Wave-synchronous exact top-128 on bf16 scores via 16-step ballot binary
// search (no LDS / atomics / barriers). Tie -> lower index via ballot rank.
// MODE 0: fp32 dense write (phase output) + bf16 in-place WB (attnv input).
// MODE 1: bf16 in-place WB only.
// Row mapping is XCD-aligned: block b handles 4 rows of head (b&7)*4+(i>>8)
// (i = b>>3), matching the score writers' / weight consumers' head->XCD map.
// ---------------------------------------------------------------------------
template<int MODE>
__global__ __launch_bounds__(256) void topk16_kernel(
    ushort_t* __restrict__ Sb, float* __restrict__ denseOut) {
  const int tid = threadIdx.x;
  const int lane = tid & 63, wv = tid >> 6;
  const int xcd = blockIdx.x & 7, i = blockIdx.x >> 3;
  const int head = xcd * 4 + (i >> 8);
  const int row = head * 1024 + (i & 255) * 4 + wv;
  ushort_t* Srow = Sb + (size_t)row * 1024;

  float scr[2][8];
  unsigned kk[2][8];
  #pragma unroll
  for (int g = 0; g < 2; ++g) {
    u16x8 v = *(const u16x8*)&Srow[g * 512 + lane * 8];
    #pragma unroll
    for (int e = 0; e < 8; ++e) {
      scr[g][e] = bf2f(v[e]);
      kk[g][e] = fkey16((unsigned)v[e]);
    }
  }

  unsigned prefix = 0, r = TOPK;
  #pragma unroll
  for (int b = 15; b >= 0; --b) {
    unsigned want = (prefix << 1) | 1u;
    unsigned cnt = 0;
    #pragma unroll
    for (int g = 0; g < 2; ++g)
      #pragma unroll
      for (int e = 0; e < 8; ++e)
        cnt += (unsigned)__popcll(__ballot((kk[g][e] >> b) == want));
    if (cnt >= r) prefix = want;
    else { prefix <<= 1; r -= cnt; }
  }
  const unsigned thr = prefix;

  float mx = -3.402823466e38f;
  #pragma unroll
  for (int g = 0; g < 2; ++g)
    #pragma unroll
    for (int e = 0; e < 8; ++e) mx = fmaxf(mx, scr[g][e]);
  #pragma unroll
  for (int off = 1; off < 64; off <<= 1) mx = fmaxf(mx, __shfl_xor(mx, off));

  const unsigned long long below = (1ull << lane) - 1ull;
  unsigned cum = 0;
  float w[2][8];
  float ps = 0.f;
  #pragma unroll
  for (int g = 0; g < 2; ++g) {
    unsigned long long bal[8];
    #pragma unroll
    for (int e = 0; e < 8; ++e) bal[e] = __ballot(kk[g][e] == thr);
    unsigned rb = cum;
    #pragma unroll
    for (int e = 0; e < 8; ++e) rb += (unsigned)__popcll(bal[e] & below);
    unsigned ownPrior = 0;
    #pragma unroll
    for (int e = 0; e < 8; ++e) {
      bool eq = (kk[g][e] == thr);
      bool sel = (kk[g][e] > thr) || (eq && (rb + ownPrior) < r);
      ownPrior += eq ? 1u : 0u;
      float ex = sel ? __expf(scr[g][e] - mx) : 0.f;
      w[g][e] = ex;
      ps += ex;
    }
    #pragma unroll
    for (int e = 0; e < 8; ++e) cum += (unsigned)__popcll(bal[e]);
  }
  float pss = ps;
  #pragma unroll
  for (int off = 1; off < 64; off <<= 1) pss += __shfl_xor(pss, off);
  const float inv = 1.f / pss;

  if (MODE == 0) {
    float* Drow = denseOut + (size_t)row * 1024;
    #pragma unroll
    for (int g = 0; g < 2; ++g) {
      *(float4*)&Drow[g * 512 + lane * 8] =
          make_float4(w[g][0] * inv, w[g][1] * inv, w[g][2] * inv, w[g][3] * inv);
      *(float4*)&Drow[g * 512 + lane * 8 + 4] =
          make_float4(w[g][4] * inv, w[g][5] * inv, w[g][6] * inv, w[g][7] * inv);
    }
  }
  #pragma unroll
  for (int g = 0; g < 2; ++g) {
    u16x8 o;
    #pragma unroll
    for (int e = 0; e < 8; ++e) o[e] = f2bf(w[g][e] * inv);
    *(u16x8*)&Srow[g * 512 + lane * 8] = o;
  }
}

// ---------- attn.V as MFMA (BM=64), 1D grid 512, XCD-swizzled ---------------
__global__ __launch_bounds__(256) void attnv_mfma(
    const ushort_t* __restrict__ Wb, const ushort_t* __restrict__ Vt,
    ushort_t* __restrict__ attn_b) {
  __shared__ ushort_t ldsA[64 * 64];
  __shared__ ushort_t ldsB[64 * 64];
  int tid = threadIdx.x;
  int orig = (blockIdx.x & 7) * 64 + (blockIdx.x >> 3);
  int bx = orig & 15, hz = orig >> 4;
  const int lane = tid & 63, wid = tid >> 6;
  const int wr = wid >> 1, wc = wid & 1;
  const int l15 = lane & 15, l4 = lane >> 4;
  const ushort_t* Wh = Wb + (size_t)hz * 1048576 + (size_t)bx * 64 * 1024;
  const ushort_t* Vh = Vt + (size_t)hz * 65536;
  f32x4 acc[2][2];
  #pragma unroll
  for (int m = 0; m < 2; ++m)
    #pragma unroll
    for (int n = 0; n < 2; ++n) acc[m][n] = (f32x4){0.f, 0.f, 0.f, 0.f};
  for (int k0 = 0; k0 < 1024; k0 += 64) {
    #pragma unroll
    for (int i = 0; i < 2; ++i) {
      int cid = tid + 256 * i;
      int rowc = cid >> 3, slot = cid & 7;
      int gc = slot ^ (rowc & 7);
      gload_lds16(&Wh[(size_t)rowc * 1024 + k0 + gc * 8], &ldsA[cid * 8]);
    }
    #pragma unroll
    for (int i = 0; i < 2; ++i) {
      int cid = tid + 256 * i;
      int rowc = cid >> 3, slot = cid & 7;
      int gc = slot ^ (rowc & 7);
      gload_lds16(&Vh[(size_t)rowc * 1024 + k0 + gc * 8], &ldsB[cid * 8]);
    }
    __syncthreads();
    #pragma unroll
    for (int ks = 0; ks < 2; ++ks) {
      short8 af[2], bfr[2];
      #pragma unroll
      for (int m = 0; m < 2; ++m) {
        int r = wr * 32 + m * 16 + l15;
        int c = ks * 4 + l4;
        af[m] = *(const short8*)&ldsA[r * 64 + (c ^ (r & 7)) * 8];
      }
      #pragma unroll
      for (int n = 0; n < 2; ++n) {
        int r = wc * 32 + n * 16 + l15;
        int c = ks * 4 + l4;
        bfr[n] = *(const short8*)&ldsB[r * 64 + (c ^ (r & 7)) * 8];
      }
      #pragma unroll
      for (int m = 0; m < 2; ++m)
        #pragma unroll
        for (int n = 0; n < 2; ++n)
          acc[m][n] = __builtin_amdgcn_mfma_f32_16x16x32_bf16(
              af[m], bfr[n], acc[m][n], 0, 0, 0);
    }
    __syncthreads();
  }
  int b = hz >> 4, h = hz & 15;
  #pragma unroll
  for (int m = 0; m < 2; ++m)
    #pragma unroll
    for (int n = 0; n < 2; ++n)
      #pragma unroll
      for (int j = 0; j < 4; ++j) {
        int t = bx * 64 + wr * 32 + m * 16 + l4 * 4 + j;
        int d = wc * 32 + n * 16 + l15;
        attn_b[((size_t)(b * T_ + t)) * DM + h * DK_ + d] = f2bf(acc[m][n][j]);
      }
}

// ---------- output projection: BM=64 x BN=128 x K=1024, grid 256 ------------
__global__ __launch_bounds__(256) void outproj_mfma(
    const ushort_t* __restrict__ A, const ushort_t* __restrict__ Wo,
    float* __restrict__ out) {
  __shared__ ushort_t ldsA[64 * 64];
  __shared__ ushort_t ldsB[128 * 64];
  int tid = threadIdx.x;
  int orig = (blockIdx.x & 7) * 32 + (blockIdx.x >> 3);
  int bx = orig & 7, by = orig >> 3;   // bx: 128-col tile, by: 64-row tile
  const int lane = tid & 63, wid = tid >> 6;
  const int wr = wid >> 1, wc = wid & 1;
  const int l15 = lane & 15, l4 = lane >> 4;
  f32x4 acc[2][4];
  #pragma unroll
  for (int m = 0; m < 2; ++m)
    #pragma unroll
    for (int n = 0; n < 4; ++n) acc[m][n] = (f32x4){0.f, 0.f, 0.f, 0.f};
  mfma_64x128_loop(A + (size_t)by * 64 * 1024,
                   Wo + (size_t)bx * 128 * 1024, ldsA, ldsB, tid, acc);
  #pragma unroll
  for (int m = 0; m < 2; ++m)
    #pragma unroll
    for (int n = 0; n < 4; ++n)
      #pragma unroll
      for (int j = 0; j < 4; ++j) {
        int r = by * 64 + wr * 32 + m * 16 + l4 * 4 + j;
        int c = bx * 128 + wc * 64 + n * 16 + l15;
        out[(size_t)r * 1024 + c] = acc[m][n][j];
      }
}

extern "C" void kernel_launch(void* const* d_in, const int* in_sizes, int n_in,
                              void* d_out, int out_size, void* d_ws, size_t ws_size,
                              hipStream_t stream) {
  (void)in_sizes; (void)n_in; (void)out_size; (void)ws_size;
  const float* x         = (const float*)d_in[0];
  const float* wq        = (const float*)d_in[1];
  const float* wk        = (const float*)d_in[2];
  const float* wre       = (const float*)d_in[3];
  const float* wim       = (const float*)d_in[4];
  const float* wv        = (const float*)d_in[5];
  const float* wo        = (const float*)d_in[6];
  const float* logit_lam = (const float*)d_in[7];
  const float* log_alpha = (const float*)d_in[8];

  float* out   = (float*)d_out;                 // (B,T,DM)
  float* dense = out + (size_t)B_ * T_ * DM;    // phase_attn (B,H,T,T) fp32 out
  // first 10 MB of dense doubles as bf16 weight scratch (wq..wv); dead after
  // proj5 and long before topk16<0> writes the dense region (stream-ordered).
  ushort_t* w5_b = (ushort_t*)dense;

  char* ws = (char*)d_ws;
  const size_t MB = (size_t)1 << 20;
  // 0-64 MB: adjacency bf16 scores -> in-place weights (prop input);
  //          later reused for phase bf16 scores -> in-place weights (attnv).
  ushort_t* A_b  = (ushort_t*)(ws + 0 * MB);
  ushort_t* S2_b = A_b;                          // phase scores (A dead)
  ushort_t* dt0  = (ushort_t*)(ws + 64 * MB);    // 8 MB Dt0 [32][128][1024]
  ushort_t* dtA  = (ushort_t*)(ws + 72 * MB);    // 8 MB ping
  ushort_t* dtB  = (ushort_t*)(ws + 80 * MB);    // 8 MB pong; P_b after prop3
  ushort_t* P_b  = dtB;                          // packed [t][Ur|Ui] bf16
  ushort_t* vt_b = (ushort_t*)(ws + 88 * MB);    // 4 MB Vt [32][64][1024]
  ushort_t* xb   = (ushort_t*)(ws + 92 * MB);    // 4 MB bf16 x; reused attn_b
  ushort_t* attn_b = xb;                         // alias (x dead after proj)
  ushort_t* qh_b = (ushort_t*)(ws + 96 * MB);    // 4 MB bf16 Q; wo_b after adj
  ushort_t* wo_b = qh_b;                         // alias (Q dead after scores)
  ushort_t* kh_b = (ushort_t*)(ws + 100 * MB);   // 4 MB bf16 K
  // total workspace: 104 MB

  const int rows = B_ * H_ * T_;  // 32768

  // 0. bf16 casts, one launch (W_O deferred until Q is dead)
  cast6_kernel<<<dim3(2048, 6), 256, 0, stream>>>(
      x, wq, wk, wre, wim, wv, xb, w5_b);

  // 1. all 5 projections (MFMA)
  proj5_mfma<<<640, 256, 0, stream>>>(xb, w5_b, qh_b, kh_b, dt0, vt_b);

  // 2. adjacency scores (bf16 -> A_b) + top-k (in-place bf16 weights)
  score_mfma<64><<<2048, 256, 0, stream>>>(qh_b, kh_b, A_b, 0.125f);
  cast_bf16_kernel<<<1024, 256, 0, stream>>>(wo, wo_b, DM * DM / 4);  // Q dead
  topk16_kernel<1><<<rows / 4, 256, 0, stream>>>(A_b, nullptr);

  // 3. topology propagation: 3 plain steps + final step fused with finalize
  prop_mfma<<<512, 256, 0, stream>>>(A_b, dt0, dtA, logit_lam);
  prop_mfma<<<512, 256, 0, stream>>>(A_b, dtA, dtB, logit_lam);
  prop_mfma<<<512, 256, 0, stream>>>(A_b, dtB, dtA, logit_lam);
  prop_final_mfma<<<512, 256, 0, stream>>>(A_b, dtA, dt0, P_b,
                                           logit_lam, log_alpha);

  // 4. phase scores, symmetric (bf16 -> S2_b over dead A) + top-k:
  //    fp32 dense output + bf16 in-place weights for attnv
  score_sym_mfma<<<1152, 256, 0, stream>>>(P_b, S2_b, 11.3137085f);
  topk16_kernel<0><<<rows / 4, 256, 0, stream>>>(S2_b, dense);

  // 5. attn . V as MFMA from bf16 weights, then output projection
  attnv_mfma<<<512, 256, 0, stream>>>(S2_b, vt_b, attn_b);
  outproj_mfma<<<256, 256, 0, stream>>>(attn_b, wo_b, out);
}